// Round 1
// baseline (726.370 us; speedup 1.0000x reference)
//
#include <hip/hip_runtime.h>
#include <cstdint>
#include <cstddef>

typedef __bf16 bf16x8 __attribute__((ext_vector_type(8)));
typedef float f32x4 __attribute__((ext_vector_type(4)));
typedef unsigned short u16;
typedef u16 u16x4 __attribute__((ext_vector_type(4)));
typedef u16 u16x8 __attribute__((ext_vector_type(8)));

// fp32 -> bf16 round-to-nearest-even
__device__ __forceinline__ u16 f2bf(float f) {
  union { float f; unsigned u; } v; v.f = f;
  return (u16)((v.u + 0x7FFFu + ((v.u >> 16) & 1u)) >> 16);
}

// async global->LDS, 16B per lane; LDS dest = uniform base + lane*16
__device__ __forceinline__ void gl_lds16(const void* g, void* l) {
  __builtin_amdgcn_global_load_lds((__attribute__((address_space(1))) void*)(g),
                                   (__attribute__((address_space(3))) void*)(l), 16, 0, 0);
}

// ---------------------------------------------------------------------------
// Pre-pass: gather (route) + transpose + fp32->bf16.
// in: [*, K, N] fp32 plane selected by route[z] (or z if route==null)
// out: [z, N, K] bf16 (n-major, so GEMM B staging == A staging pattern)
// ---------------------------------------------------------------------------
__global__ void transpose_cvt(const float* __restrict__ in, const int* __restrict__ route,
                              u16* __restrict__ out, int K, int N) {
  __shared__ float t[32][33];
  const int a = blockIdx.z;
  const int src = route ? route[a] : a;
  const float* ip = in + (size_t)src * K * N;
  u16* op = out + (size_t)a * K * N;
  const int k0 = blockIdx.x * 32, n0 = blockIdx.y * 32;
  const int tx = threadIdx.x, ty = threadIdx.y;  // (32, 8)
#pragma unroll
  for (int i = 0; i < 4; ++i)
    t[ty + i * 8][tx] = ip[(size_t)(k0 + ty + i * 8) * N + n0 + tx];
  __syncthreads();
#pragma unroll
  for (int i = 0; i < 4; ++i)
    op[(size_t)(n0 + ty + i * 8) * K + k0 + tx] = f2bf(t[tx][ty + i * 8]);
}

// ---------------------------------------------------------------------------
// Layer 1: x1 = relu(x0 @ Ws + bs).  A fp32 (inline cvt, register staging),
// B bf16 via global_load_lds.  C written bf16 to (a, b, n) planes.
// Tiles: BM=128 BN=128 BK=32, 256 thr / 4 waves, wave = 64x64 (4x4 MFMA).
// ---------------------------------------------------------------------------
__global__ __launch_bounds__(256)
void gemm_l1(const float* __restrict__ X0, const u16* __restrict__ Wt,
             const float* __restrict__ bsh, u16* __restrict__ X1) {
  __shared__ u16 As[128 * 32];
  __shared__ u16 Bs[128 * 32];
  const int tid = threadIdx.x;
  const int w = tid >> 6, l = tid & 63;
  const int r = l & 15, q = l >> 4;
  const int m0 = blockIdx.y * 128, n0 = blockIdx.x * 128;

  // A staging slots (register path): p0 = tid (rows 0..63), p1 = tid+256 (rows 64..127)
  const int p0 = tid, p1 = tid + 256;
  const int am0 = p0 >> 2, am1 = p1 >> 2;
  const float* gA0 = X0 + (size_t)(m0 + am0) * 512 + (((p0 & 3) ^ ((am0 >> 1) & 3)) << 3);
  const float* gA1 = X0 + (size_t)(m0 + am1) * 512 + (((p1 & 3) ^ ((am1 >> 1) & 3)) << 3);

  // B staging slots (global_load_lds): slot = (w*2+j)*64 + l
  const int pb0 = (w * 2 + 0) * 64 + l, pb1 = (w * 2 + 1) * 64 + l;
  const int bn0 = pb0 >> 2, bn1 = pb1 >> 2;
  const u16* gB0 = Wt + (size_t)(n0 + bn0) * 512 + (((pb0 & 3) ^ ((bn0 >> 1) & 3)) << 3);
  const u16* gB1 = Wt + (size_t)(n0 + bn1) * 512 + (((pb1 & 3) ^ ((bn1 >> 1) & 3)) << 3);
  u16* lB0 = &Bs[(w * 2 + 0) * 512];
  u16* lB1 = &Bs[(w * 2 + 1) * 512];

  const int wm = (w & 1) * 64, wn = (w >> 1) * 64;
  int aoff[4], boff[4];
#pragma unroll
  for (int t = 0; t < 4; ++t) {
    const int m = wm + t * 16 + r;
    aoff[t] = m * 32 + ((q ^ ((m >> 1) & 3)) << 3);
    const int n = wn + t * 16 + r;
    boff[t] = n * 32 + ((q ^ ((n >> 1) & 3)) << 3);
  }

  f32x4 acc[4][4] = {};
  for (int kt = 0; kt < 16; ++kt) {
    const float4 u0 = *(const float4*)(gA0);
    const float4 u1 = *(const float4*)(gA0 + 4);
    const float4 u2 = *(const float4*)(gA1);
    const float4 u3 = *(const float4*)(gA1 + 4);
    gA0 += 32; gA1 += 32;
    __syncthreads();              // previous iter's LDS reads done
    gl_lds16(gB0, lB0); gB0 += 32;
    gl_lds16(gB1, lB1); gB1 += 32;
    const u16x8 d0 = { f2bf(u0.x), f2bf(u0.y), f2bf(u0.z), f2bf(u0.w),
                       f2bf(u1.x), f2bf(u1.y), f2bf(u1.z), f2bf(u1.w) };
    const u16x8 d1 = { f2bf(u2.x), f2bf(u2.y), f2bf(u2.z), f2bf(u2.w),
                       f2bf(u3.x), f2bf(u3.y), f2bf(u3.z), f2bf(u3.w) };
    *(u16x8*)&As[p0 * 8] = d0;
    *(u16x8*)&As[p1 * 8] = d1;
    __syncthreads();              // staging visible (vmcnt+lgkm drained by barrier)
    bf16x8 af[4], bv[4];
#pragma unroll
    for (int t = 0; t < 4; ++t) af[t] = *(const bf16x8*)&As[aoff[t]];
#pragma unroll
    for (int t = 0; t < 4; ++t) bv[t] = *(const bf16x8*)&Bs[boff[t]];
#pragma unroll
    for (int mt = 0; mt < 4; ++mt)
#pragma unroll
      for (int nt = 0; nt < 4; ++nt)  // swapped operands => lane holds 4 consecutive n
        acc[mt][nt] = __builtin_amdgcn_mfma_f32_16x16x32_bf16(bv[nt], af[mt], acc[mt][nt], 0, 0, 0);
  }
  // epilogue: C[m][n]; lane: m = r, n = 4q+t within each 16x16 frag
#pragma unroll
  for (int mt = 0; mt < 4; ++mt) {
    const int m = m0 + wm + mt * 16 + r;            // flat row = b*32 + a
    u16* orow = X1 + ((size_t)(m & 31) * 4096 + (size_t)(m >> 5)) * 512;
#pragma unroll
    for (int nt = 0; nt < 4; ++nt) {
      const int n = n0 + wn + nt * 16 + q * 4;
      const float4 bb = *(const float4*)&bsh[n];
      const f32x4 v = acc[mt][nt];
      const u16x4 d = { f2bf(fmaxf(v.x + bb.x, 0.f)), f2bf(fmaxf(v.y + bb.y, 0.f)),
                        f2bf(fmaxf(v.z + bb.z, 0.f)), f2bf(fmaxf(v.w + bb.w, 0.f)) };
      *(u16x4*)&orow[n] = d;
    }
  }
}

// ---------------------------------------------------------------------------
// Layer 2: h[a] = relu(x1[a] @ Wg1[a] + bg1[a]).  All-bf16, full global_load_lds.
// ---------------------------------------------------------------------------
__global__ __launch_bounds__(256)
void gemm_l2(const u16* __restrict__ X1, const u16* __restrict__ W1t,
             const float* __restrict__ b1, const int* __restrict__ route,
             u16* __restrict__ H) {
  __shared__ u16 As[128 * 32];
  __shared__ u16 Bs[128 * 32];
  const int tid = threadIdx.x;
  const int w = tid >> 6, l = tid & 63;
  const int r = l & 15, q = l >> 4;
  const int a = blockIdx.z;
  const int m0 = blockIdx.y * 128, n0 = blockIdx.x * 128;
  const u16* Ap = X1 + (size_t)a * 4096 * 512;
  const u16* Bp = W1t + (size_t)a * 512 * 512;

  const int pa0 = (w * 2 + 0) * 64 + l, pa1 = (w * 2 + 1) * 64 + l;
  const int am0 = pa0 >> 2, am1 = pa1 >> 2;
  const int sc0 = ((pa0 & 3) ^ ((am0 >> 1) & 3)) << 3;
  const int sc1 = ((pa1 & 3) ^ ((am1 >> 1) & 3)) << 3;
  const u16* gA0 = Ap + (size_t)(m0 + am0) * 512 + sc0;
  const u16* gA1 = Ap + (size_t)(m0 + am1) * 512 + sc1;
  const u16* gB0 = Bp + (size_t)(n0 + am0) * 512 + sc0;
  const u16* gB1 = Bp + (size_t)(n0 + am1) * 512 + sc1;
  u16* lA0 = &As[(w * 2 + 0) * 512];
  u16* lA1 = &As[(w * 2 + 1) * 512];
  u16* lB0 = &Bs[(w * 2 + 0) * 512];
  u16* lB1 = &Bs[(w * 2 + 1) * 512];

  const int wm = (w & 1) * 64, wn = (w >> 1) * 64;
  int aoff[4], boff[4];
#pragma unroll
  for (int t = 0; t < 4; ++t) {
    const int m = wm + t * 16 + r;
    aoff[t] = m * 32 + ((q ^ ((m >> 1) & 3)) << 3);
    const int n = wn + t * 16 + r;
    boff[t] = n * 32 + ((q ^ ((n >> 1) & 3)) << 3);
  }

  f32x4 acc[4][4] = {};
  for (int kt = 0; kt < 16; ++kt) {
    __syncthreads();
    gl_lds16(gA0, lA0); gA0 += 32;
    gl_lds16(gA1, lA1); gA1 += 32;
    gl_lds16(gB0, lB0); gB0 += 32;
    gl_lds16(gB1, lB1); gB1 += 32;
    __syncthreads();
    bf16x8 af[4], bv[4];
#pragma unroll
    for (int t = 0; t < 4; ++t) af[t] = *(const bf16x8*)&As[aoff[t]];
#pragma unroll
    for (int t = 0; t < 4; ++t) bv[t] = *(const bf16x8*)&Bs[boff[t]];
#pragma unroll
    for (int mt = 0; mt < 4; ++mt)
#pragma unroll
      for (int nt = 0; nt < 4; ++nt)
        acc[mt][nt] = __builtin_amdgcn_mfma_f32_16x16x32_bf16(bv[nt], af[mt], acc[mt][nt], 0, 0, 0);
  }
  const int rt = route[a];
#pragma unroll
  for (int mt = 0; mt < 4; ++mt) {
    const int m = m0 + wm + mt * 16 + r;
    u16* orow = H + ((size_t)a * 4096 + m) * 512;
#pragma unroll
    for (int nt = 0; nt < 4; ++nt) {
      const int n = n0 + wn + nt * 16 + q * 4;
      const float4 bb = *(const float4*)&b1[(size_t)rt * 512 + n];
      const f32x4 v = acc[mt][nt];
      const u16x4 d = { f2bf(fmaxf(v.x + bb.x, 0.f)), f2bf(fmaxf(v.y + bb.y, 0.f)),
                        f2bf(fmaxf(v.z + bb.z, 0.f)), f2bf(fmaxf(v.w + bb.w, 0.f)) };
      *(u16x4*)&orow[n] = d;
    }
  }
}

// ---------------------------------------------------------------------------
// Layer 3: x2[a] = h[a] @ Wg2[a] + bg2[a].  BM=128 BN=32 BK=64, fp32 out.
// ---------------------------------------------------------------------------
__global__ __launch_bounds__(256)
void gemm_l3(const u16* __restrict__ Hs, const u16* __restrict__ W2t,
             const float* __restrict__ b2, const int* __restrict__ route,
             float* __restrict__ Out) {
  __shared__ u16 As[128 * 64];
  __shared__ u16 Bs[32 * 64];
  const int tid = threadIdx.x;
  const int w = tid >> 6, l = tid & 63;
  const int r = l & 15, q = l >> 4;
  const int a = blockIdx.z;
  const int m0 = blockIdx.x * 128;
  const u16* Ap = Hs + (size_t)a * 4096 * 512;
  const u16* Bp = W2t + (size_t)a * 32 * 512;

  const u16* gA[4]; u16* lA[4];
#pragma unroll
  for (int j = 0; j < 4; ++j) {
    const int p = (w * 4 + j) * 64 + l;
    const int m = p >> 3, s = p & 7;
    gA[j] = Ap + (size_t)(m0 + m) * 512 + ((s ^ (m & 7)) << 3);
    lA[j] = &As[(w * 4 + j) * 512];
  }
  const int pb = w * 64 + l;
  const int bn = pb >> 3, bsi = pb & 7;
  const u16* gB = Bp + (size_t)bn * 512 + ((bsi ^ (bn & 7)) << 3);
  u16* lB = &Bs[w * 512];

  f32x4 acc[2][2] = {};
  for (int kt = 0; kt < 8; ++kt) {
    __syncthreads();
#pragma unroll
    for (int j = 0; j < 4; ++j) { gl_lds16(gA[j], lA[j]); gA[j] += 64; }
    gl_lds16(gB, lB); gB += 64;
    __syncthreads();
#pragma unroll
    for (int ks = 0; ks < 2; ++ks) {
      bf16x8 af[2], bv[2];
#pragma unroll
      for (int t = 0; t < 2; ++t) {
        const int m = w * 32 + t * 16 + r;
        af[t] = *(const bf16x8*)&As[m * 64 + ((((ks << 2) + q) ^ (m & 7)) << 3)];
        const int n = t * 16 + r;
        bv[t] = *(const bf16x8*)&Bs[n * 64 + ((((ks << 2) + q) ^ (n & 7)) << 3)];
      }
#pragma unroll
      for (int mt = 0; mt < 2; ++mt)
#pragma unroll
        for (int nt = 0; nt < 2; ++nt)
          acc[mt][nt] = __builtin_amdgcn_mfma_f32_16x16x32_bf16(bv[nt], af[mt], acc[mt][nt], 0, 0, 0);
    }
  }
  const int rt = route[a];
#pragma unroll
  for (int mt = 0; mt < 2; ++mt) {
    const int m = m0 + w * 32 + mt * 16 + r;
    float* orow = Out + (size_t)m * 1024 + a * 32;
#pragma unroll
    for (int nt = 0; nt < 2; ++nt) {
      const int n = nt * 16 + q * 4;
      const float4 bb = *(const float4*)&b2[rt * 32 + n];
      const f32x4 v = acc[mt][nt];
      const float4 o = { v.x + bb.x, v.y + bb.y, v.z + bb.z, v.w + bb.w };
      *(float4*)&orow[n] = o;
    }
  }
}

// ---------------------------------------------------------------------------
extern "C" void kernel_launch(void* const* d_in, const int* in_sizes, int n_in,
                              void* d_out, int out_size, void* d_ws, size_t ws_size,
                              hipStream_t stream) {
  (void)in_sizes; (void)n_in; (void)out_size; (void)ws_size;
  const float* x0  = (const float*)d_in[0];
  const float* Wsh = (const float*)d_in[1];
  const float* bsh = (const float*)d_in[2];
  const float* W1  = (const float*)d_in[3];
  const float* b1  = (const float*)d_in[4];
  const float* W2  = (const float*)d_in[5];
  const float* b2  = (const float*)d_in[6];
  const int* route = (const int*)d_in[7];
  float* out = (float*)d_out;

  char* ws = (char*)d_ws;
  u16* Wst = (u16*)(ws + 0);                                    // 512*512*2   = 512 KB
  u16* W1t = (u16*)(ws + 524288);                               // 32*512*512*2 = 16 MB
  u16* W2t = (u16*)(ws + 524288 + 16777216);                    // 32*32*512*2  = 1 MB
  u16* X1  = (u16*)(ws + 18350080);                             // 32*4096*512*2 = 128 MB
  u16* Hb  = (u16*)(ws + 18350080 + 134217728);                 // 128 MB

  transpose_cvt<<<dim3(16, 16, 1),  dim3(32, 8), 0, stream>>>(Wsh, nullptr, Wst, 512, 512);
  transpose_cvt<<<dim3(16, 16, 32), dim3(32, 8), 0, stream>>>(W1, route, W1t, 512, 512);
  transpose_cvt<<<dim3(16, 1, 32),  dim3(32, 8), 0, stream>>>(W2, route, W2t, 512, 32);
  gemm_l1<<<dim3(4, 1024, 1), 256, 0, stream>>>(x0, Wst, bsh, X1);
  gemm_l2<<<dim3(4, 32, 32),  256, 0, stream>>>(X1, W1t, b1, route, Hb);
  gemm_l3<<<dim3(32, 1, 32),  256, 0, stream>>>(Hb, W2t, b2, route, out);
}

// Round 2
// 614.644 us; speedup vs baseline: 1.1818x; 1.1818x over previous
//
#include <hip/hip_runtime.h>
#include <cstdint>
#include <cstddef>

typedef __bf16 bf16x8 __attribute__((ext_vector_type(8)));
typedef float f32x4 __attribute__((ext_vector_type(4)));
typedef unsigned short u16;
typedef u16 u16x4 __attribute__((ext_vector_type(4)));

// fp32 -> bf16 round-to-nearest-even
__device__ __forceinline__ u16 f2bf(float f) {
  union { float f; unsigned u; } v; v.f = f;
  return (u16)((v.u + 0x7FFFu + ((v.u >> 16) & 1u)) >> 16);
}

// async global->LDS, 16B per lane; LDS dest = uniform base + lane*16
__device__ __forceinline__ void gl_lds16(const void* g, void* l) {
  __builtin_amdgcn_global_load_lds((__attribute__((address_space(1))) void*)(g),
                                   (__attribute__((address_space(3))) void*)(l), 16, 0, 0);
}

// ---------------------------------------------------------------------------
// Pre-pass: gather (route) + transpose + fp32->bf16.
// in: [*, K, N] fp32 plane selected by route[z] (or z if route==null)
// out: [z, N, K] bf16 (n-major)
// ---------------------------------------------------------------------------
__global__ void transpose_cvt(const float* __restrict__ in, const int* __restrict__ route,
                              u16* __restrict__ out, int K, int N) {
  __shared__ float t[32][33];
  const int a = blockIdx.z;
  const int src = route ? route[a] : a;
  const float* ip = in + (size_t)src * K * N;
  u16* op = out + (size_t)a * K * N;
  const int k0 = blockIdx.x * 32, n0 = blockIdx.y * 32;
  const int tx = threadIdx.x, ty = threadIdx.y;  // (32, 8)
#pragma unroll
  for (int i = 0; i < 4; ++i)
    t[ty + i * 8][tx] = ip[(size_t)(k0 + ty + i * 8) * N + n0 + tx];
  __syncthreads();
#pragma unroll
  for (int i = 0; i < 4; ++i)
    op[(size_t)(n0 + ty + i * 8) * K + k0 + tx] = f2bf(t[tx][ty + i * 8]);
}

// ---------------------------------------------------------------------------
// Fused 3-layer MLP per (64-row batch tile, agent).
// Phase 1: X = relu(x0 @ Ws + bs)          (bf16 tile in LDS, never HBM)
// Phase 2: h = relu(X @ W1[a]^T + b1[a])   (acc in regs, h overwrites X)
// Phase 3: out = h @ W2[a]^T + b2[a]       (direct fp32 store)
// 512 threads / 8 waves; wave n-slice 64; double-buffered B staging.
// ---------------------------------------------------------------------------
__global__ __launch_bounds__(512)
void fused_mlp(const float* __restrict__ X0, const u16* __restrict__ Wst,
               const float* __restrict__ bsh, const u16* __restrict__ W1t,
               const float* __restrict__ b1, const u16* __restrict__ W2t,
               const float* __restrict__ b2, const int* __restrict__ route,
               float* __restrict__ Out) {
  __shared__ u16 lds[69632];                 // 136 KB
  u16* Xs = lds;                             // [64][512] bf16, g' = (k>>3) ^ (m&7)
  u16* Bp0 = lds + 32768;                    // [512 n][32 k] staged B, dbuf 0
  u16* Bp1 = lds + 49152;                    // dbuf 1
  u16* Ap0 = lds + 65536;                    // [64 m][32 k] staged A (phase 1), dbuf 0
  u16* Ap1 = lds + 67584;                    // dbuf 1

  const int tid = threadIdx.x;
  const int w = tid >> 6, l = tid & 63;
  const int r = l & 15, q = l >> 4;
  const int a = blockIdx.y;
  const int b0 = blockIdx.x * 64;
  const int rt = route[a];

  // fragment read offsets for [row][32k] staged tiles (granule swizzle s^((r>>1)&3))
  int aoff[4], boff[4];
#pragma unroll
  for (int t = 0; t < 4; ++t) {
    aoff[t] = (t * 16 + r) * 32 + ((q ^ ((r >> 1) & 3)) << 3);
    boff[t] = (w * 64 + t * 16 + r) * 32 + ((q ^ ((r >> 1) & 3)) << 3);
  }

  // B staging: 4 x 16B slots per thread, dst contiguous in slot id (wave-uniform+lane*16)
  int bdst[4]; int bsrc[4];
#pragma unroll
  for (int c = 0; c < 4; ++c) {
    const int p2 = c * 512 + tid;
    const int n = p2 >> 2, s = p2 & 3;
    bsrc[c] = n * 512 + ((s ^ ((n >> 1) & 3)) << 3);
    bdst[c] = p2 * 8;
  }

  // phase-1 A: one float4 of x0 per thread per iter, inline cvt -> LDS
  const int arow = tid >> 3, akq = tid & 7;
  const float* gA = X0 + ((size_t)(b0 + arow) * 32 + a) * 512 + akq * 4;
  const int adst = arow * 32 + (((akq >> 1) ^ ((arow >> 1) & 3)) << 3) + (akq & 1) * 4;

  f32x4 acc[4][4];

  // ======================= phase 1 =======================
#pragma unroll
  for (int mt = 0; mt < 4; ++mt)
#pragma unroll
    for (int nt = 0; nt < 4; ++nt) acc[mt][nt] = (f32x4){0.f, 0.f, 0.f, 0.f};

  float4 av = *(const float4*)gA;
#pragma unroll
  for (int c = 0; c < 4; ++c) gl_lds16(Wst + bsrc[c], &Bp0[bdst[c]]);
  {
    const u16x4 d = { f2bf(av.x), f2bf(av.y), f2bf(av.z), f2bf(av.w) };
    *(u16x4*)&Ap0[adst] = d;
  }
  __syncthreads();

  for (int kt = 0; kt < 16; ++kt) {
    const u16* Bc = (kt & 1) ? Bp1 : Bp0;
    const u16* Ac = (kt & 1) ? Ap1 : Ap0;
    u16* Bn = (kt & 1) ? Bp0 : Bp1;
    u16* An = (kt & 1) ? Ap0 : Ap1;
    if (kt < 15) {
      av = *(const float4*)(gA + (kt + 1) * 32);
#pragma unroll
      for (int c = 0; c < 4; ++c)
        gl_lds16(Wst + bsrc[c] + (kt + 1) * 32, &Bn[bdst[c]]);
    }
    bf16x8 af[4], bv[4];
#pragma unroll
    for (int t = 0; t < 4; ++t) af[t] = *(const bf16x8*)&Ac[aoff[t]];
#pragma unroll
    for (int t = 0; t < 4; ++t) bv[t] = *(const bf16x8*)&Bc[boff[t]];
#pragma unroll
    for (int mt = 0; mt < 4; ++mt)
#pragma unroll
      for (int nt = 0; nt < 4; ++nt)   // swapped operands => lane holds m=r, n=q*4+t
        acc[mt][nt] = __builtin_amdgcn_mfma_f32_16x16x32_bf16(bv[nt], af[mt], acc[mt][nt], 0, 0, 0);
    if (kt < 15) {
      const u16x4 d = { f2bf(av.x), f2bf(av.y), f2bf(av.z), f2bf(av.w) };
      *(u16x4*)&An[adst] = d;
    }
    __syncthreads();
  }
  // epilogue: relu + bias -> Xs
#pragma unroll
  for (int mt = 0; mt < 4; ++mt) {
    const int m = mt * 16 + r;
#pragma unroll
    for (int nt = 0; nt < 4; ++nt) {
      const int col = w * 64 + nt * 16 + q * 4;
      const int gp = (col >> 3) ^ (m & 7);
      const float4 bb = *(const float4*)&bsh[col];
      const f32x4 v = acc[mt][nt];
      const u16x4 d = { f2bf(fmaxf(v.x + bb.x, 0.f)), f2bf(fmaxf(v.y + bb.y, 0.f)),
                        f2bf(fmaxf(v.z + bb.z, 0.f)), f2bf(fmaxf(v.w + bb.w, 0.f)) };
      *(u16x4*)&Xs[m * 512 + gp * 8 + (q & 1) * 4] = d;
    }
  }

  // ======================= phase 2 =======================
  const u16* W1a = W1t + (size_t)a * 262144;
#pragma unroll
  for (int c = 0; c < 4; ++c) gl_lds16(W1a + bsrc[c], &Bp0[bdst[c]]);
  __syncthreads();   // Xs writes + B0 staging drained

#pragma unroll
  for (int mt = 0; mt < 4; ++mt)
#pragma unroll
    for (int nt = 0; nt < 4; ++nt) acc[mt][nt] = (f32x4){0.f, 0.f, 0.f, 0.f};

  for (int kt = 0; kt < 16; ++kt) {
    const u16* Bc = (kt & 1) ? Bp1 : Bp0;
    u16* Bn = (kt & 1) ? Bp0 : Bp1;
    if (kt < 15) {
#pragma unroll
      for (int c = 0; c < 4; ++c)
        gl_lds16(W1a + bsrc[c] + (kt + 1) * 32, &Bn[bdst[c]]);
    }
    bf16x8 af[4], bv[4];
#pragma unroll
    for (int t = 0; t < 4; ++t) {
      const int m = t * 16 + r;
      af[t] = *(const bf16x8*)&Xs[m * 512 + (((kt * 4 + q) ^ (m & 7)) << 3)];
    }
#pragma unroll
    for (int t = 0; t < 4; ++t) bv[t] = *(const bf16x8*)&Bc[boff[t]];
#pragma unroll
    for (int mt = 0; mt < 4; ++mt)
#pragma unroll
      for (int nt = 0; nt < 4; ++nt)
        acc[mt][nt] = __builtin_amdgcn_mfma_f32_16x16x32_bf16(bv[nt], af[mt], acc[mt][nt], 0, 0, 0);
    __syncthreads();
  }

  // phase-3 staging first (overlaps epilogue VALU): W2t[a] (32x512) -> Bp0 as [32 n][512 k]
  const u16* W2a = W2t + (size_t)a * 16384;
#pragma unroll
  for (int c = 0; c < 4; ++c) {
    const int p2 = c * 512 + tid;
    const int n = p2 >> 6, gs = p2 & 63;
    gl_lds16(W2a + (size_t)n * 512 + ((gs ^ (n & 7)) << 3), &Bp0[p2 * 8]);
  }
  // phase-2 epilogue: relu + bias, h overwrites Xs (all Xs reads done at final barrier)
#pragma unroll
  for (int mt = 0; mt < 4; ++mt) {
    const int m = mt * 16 + r;
#pragma unroll
    for (int nt = 0; nt < 4; ++nt) {
      const int col = w * 64 + nt * 16 + q * 4;
      const int gp = (col >> 3) ^ (m & 7);
      const float4 bb = *(const float4*)&b1[(size_t)rt * 512 + col];
      const f32x4 v = acc[mt][nt];
      const u16x4 d = { f2bf(fmaxf(v.x + bb.x, 0.f)), f2bf(fmaxf(v.y + bb.y, 0.f)),
                        f2bf(fmaxf(v.z + bb.z, 0.f)), f2bf(fmaxf(v.w + bb.w, 0.f)) };
      *(u16x4*)&Xs[m * 512 + gp * 8 + (q & 1) * 4] = d;
    }
  }
  __syncthreads();

  // ======================= phase 3 =======================
  // out tile 64x32 = 8 frags; wave w owns frag (mt3 = w&3, nt3 = w>>2)
  {
    const int mt3 = w & 3, nt3 = w >> 2;
    const int m = mt3 * 16 + r;
    const int n = nt3 * 16 + r;
    f32x4 o = (f32x4){0.f, 0.f, 0.f, 0.f};
#pragma unroll
    for (int kt = 0; kt < 16; ++kt) {
      const bf16x8 af = *(const bf16x8*)&Xs[m * 512 + (((kt * 4 + q) ^ (m & 7)) << 3)];
      const bf16x8 bf = *(const bf16x8*)&Bp0[n * 512 + (((kt * 4 + q) ^ (n & 7)) << 3)];
      o = __builtin_amdgcn_mfma_f32_16x16x32_bf16(bf, af, o, 0, 0, 0);
    }
    const int col = nt3 * 16 + q * 4;
    const float4 bb = *(const float4*)&b2[rt * 32 + col];
    const float4 res = { o.x + bb.x, o.y + bb.y, o.z + bb.z, o.w + bb.w };
    *(float4*)&Out[(size_t)(b0 + m) * 1024 + a * 32 + col] = res;
  }
}

// ---------------------------------------------------------------------------
extern "C" void kernel_launch(void* const* d_in, const int* in_sizes, int n_in,
                              void* d_out, int out_size, void* d_ws, size_t ws_size,
                              hipStream_t stream) {
  (void)in_sizes; (void)n_in; (void)out_size; (void)ws_size;
  const float* x0  = (const float*)d_in[0];
  const float* Wsh = (const float*)d_in[1];
  const float* bsh = (const float*)d_in[2];
  const float* W1  = (const float*)d_in[3];
  const float* b1  = (const float*)d_in[4];
  const float* W2  = (const float*)d_in[5];
  const float* b2  = (const float*)d_in[6];
  const int* route = (const int*)d_in[7];
  float* out = (float*)d_out;

  char* ws = (char*)d_ws;
  u16* Wst = (u16*)(ws + 0);                      // 512*512*2    = 512 KB  [n][k]
  u16* W1t = (u16*)(ws + 524288);                 // 32*512*512*2 = 16 MB   [a][n][k]
  u16* W2t = (u16*)(ws + 524288 + 16777216);      // 32*32*512*2  = 1 MB    [a][n][k]

  transpose_cvt<<<dim3(16, 16, 1),  dim3(32, 8), 0, stream>>>(Wsh, nullptr, Wst, 512, 512);
  transpose_cvt<<<dim3(16, 16, 32), dim3(32, 8), 0, stream>>>(W1, route, W1t, 512, 512);
  transpose_cvt<<<dim3(16, 1, 32),  dim3(32, 8), 0, stream>>>(W2, route, W2t, 512, 32);
  fused_mlp<<<dim3(64, 32), 512, 0, stream>>>(x0, Wst, bsh, W1t, b1, W2t, b2, route, out);
}